// Round 1
// baseline (79.185 us; speedup 1.0000x reference)
//
#include <hip/hip_runtime.h>
#include <math.h>

#define F 128
#define D 256
#define N_CATE 18
#define P 8

// One 64-lane wave per edge. Lane l owns features {2l, 2l+1} (float2).
__global__ __launch_bounds__(256) void score_predictor_kernel(
    const float* __restrict__ gnn_emb_src,   // (N_SRC, D)
    const float* __restrict__ gnn_emb_dst,   // (N_DST, D)
    const float* __restrict__ news_pref,     // (N_DST, N_CATE, P, D)
    const float* __restrict__ last_update,   // (N_DST, N_CATE, P)
    const float* __restrict__ time_arr,      // (E,)
    const int*   __restrict__ cate_id,       // (N_SRC,)
    const int*   __restrict__ src_idx,       // (E,)
    const int*   __restrict__ dst_idx,       // (E,)
    float* __restrict__ out,
    int E)
{
    const int wave = (int)((blockIdx.x * blockDim.x + threadIdx.x) >> 6);
    const int lane = (int)(threadIdx.x & 63);
    if (wave >= E) return;
    const int e = wave;

    // Per-edge uniform scalars (uniform across the wave -> scalar loads).
    const int s = src_idx[e];
    const int d = dst_idx[e];
    const int c = cate_id[s];
    const float t0 = time_arr[0];

    const float* __restrict__ srow = gnn_emb_src + (size_t)s * D;
    const float* __restrict__ drow = gnn_emb_dst + (size_t)d * D;
    const size_t dc = (size_t)d * N_CATE + (size_t)c;
    const float* __restrict__ prow = news_pref + dc * (size_t)(P * D);
    const float* __restrict__ lrow = last_update + dc * (size_t)P;

    const float2 src2 = *(const float2*)(srow + 2 * lane);
    const float2 tgt2 = *(const float2*)(drow + 2 * lane);

    // decay weights w[p] = exp(-(t0 - lut[p]))
    float w[P];
#pragma unroll
    for (int p = 0; p < P; ++p) {
        w[p] = __expf(lrow[p] - t0);
    }

    // decayed pref_emb fragments + per-lane partial scores
    float2 pe[P];
    float sc[P];
#pragma unroll
    for (int p = 0; p < P; ++p) {
        const float2 pr = *(const float2*)(prow + p * D + 2 * lane);
        const float wp = w[p];
        const float omw = 1.0f - wp;
        pe[p].x = pr.x * wp + tgt2.x * omw;
        pe[p].y = pr.y * wp + tgt2.y * omw;
        sc[p] = src2.x * pe[p].x + src2.y * pe[p].y;
    }

    // butterfly reduce all 8 scores across the 64-lane wave
#pragma unroll
    for (int m = 32; m >= 1; m >>= 1) {
#pragma unroll
        for (int p = 0; p < P; ++p) {
            sc[p] += __shfl_xor(sc[p], m, 64);
        }
    }

    // softmax over P (replicated on every lane)
    const float inv_sqrtF = 0.088388347648318447f; // 1/sqrt(128)
    float mx = -INFINITY;
#pragma unroll
    for (int p = 0; p < P; ++p) {
        sc[p] *= inv_sqrtF;
        mx = fmaxf(mx, sc[p]);
    }
    float sum = 0.0f;
    float a[P];
#pragma unroll
    for (int p = 0; p < P; ++p) {
        a[p] = __expf(sc[p] - mx);
        sum += a[p];
    }
    const float inv = 1.0f / sum;

    // dst_pref_emb fragment = sum_p attn[p] * pe[p]
    float2 dpe = make_float2(0.0f, 0.0f);
#pragma unroll
    for (int p = 0; p < P; ++p) {
        const float ap = a[p] * inv;
        dpe.x += ap * pe[p].x;
        dpe.y += ap * pe[p].y;
    }

    // final dot: sum_f src_emb[f] * dst_pref_emb[f]
    float part = src2.x * dpe.x + src2.y * dpe.y;
#pragma unroll
    for (int m = 32; m >= 1; m >>= 1) {
        part += __shfl_xor(part, m, 64);
    }
    if (lane == 0) {
        out[e] = part;
    }
}

extern "C" void kernel_launch(void* const* d_in, const int* in_sizes, int n_in,
                              void* d_out, int out_size, void* d_ws, size_t ws_size,
                              hipStream_t stream) {
    const float* gnn_emb_src = (const float*)d_in[0];
    const float* gnn_emb_dst = (const float*)d_in[1];
    const float* news_pref   = (const float*)d_in[2];
    const float* last_update = (const float*)d_in[3];
    const float* time_arr    = (const float*)d_in[4];
    const int*   cate_id     = (const int*)d_in[5];
    const int*   src_idx     = (const int*)d_in[6];
    const int*   dst_idx     = (const int*)d_in[7];
    float* out = (float*)d_out;

    const int E = in_sizes[6];           // src_idx length
    const int waves_per_block = 256 / 64;
    const int grid = (E + waves_per_block - 1) / waves_per_block;

    score_predictor_kernel<<<grid, 256, 0, stream>>>(
        gnn_emb_src, gnn_emb_dst, news_pref, last_update, time_arr,
        cate_id, src_idx, dst_idx, out, E);
}